// Round 8
// baseline (88.000 us; speedup 1.0000x reference)
//
#include <hip/hip_runtime.h>
#include <hip/hip_bf16.h>
#include <math.h>

#define NROWS 4096
#define DDIM  512
#define INV_TAU 1.25f

typedef __attribute__((ext_vector_type(8))) short short8;
typedef __attribute__((ext_vector_type(4))) float f32x4;

__device__ inline void gload_lds16(const void* g, void* l) {
  __builtin_amdgcn_global_load_lds(
      (const __attribute__((address_space(1))) void*)g,
      (__attribute__((address_space(3))) void*)l, 16, 0, 0);
}

__device__ inline unsigned short f2bf(float f) {
  __hip_bfloat16 h = __float2bfloat16(f);
  return __builtin_bit_cast(unsigned short, h);
}
__device__ inline float bf2f(unsigned short u) {
  return __bfloat162float(__builtin_bit_cast(__hip_bfloat16, u));
}

// fp8 e4m3 (positive-only range used: s in [0.28, 3.6], all normal)
__device__ inline unsigned f2e4m3(float s) {
  unsigned b = __builtin_bit_cast(unsigned, s);
  return (b + 0x80000u - 0x3C000000u) >> 20;   // round-nearest, exp bias 7
}
__device__ inline float e4m32f(unsigned u8) {
  return __builtin_bit_cast(float, (u8 << 20) + 0x3C000000u);
}

// ---------------------------------------------------------------------------
// Kernel 1: f32 -> bf16 conversion for v1, v2, W ; zero the nsq accumulators.
// ---------------------------------------------------------------------------
__global__ void convert_kernel(const float* __restrict__ v1,
                               const float* __restrict__ v2,
                               const float* __restrict__ W,
                               unsigned short* __restrict__ v1b,
                               unsigned short* __restrict__ v2b,
                               unsigned short* __restrict__ Wb,
                               float* __restrict__ nsq1,
                               float* __restrict__ nsq2) {
  int idx = blockIdx.x * blockDim.x + threadIdx.x;
  if (idx < NROWS) { nsq1[idx] = 0.f; nsq2[idx] = 0.f; }
  const int TOTV = (NROWS * DDIM) / 4;
  const int TOTW = (DDIM * DDIM) / 4;
  const int total = 2 * TOTV + TOTW;
  const int stride = gridDim.x * blockDim.x;
  for (int i = idx; i < total; i += stride) {
    const float4* src; unsigned short* dst; int j;
    if (i < TOTV)            { src = (const float4*)v1; dst = v1b; j = i; }
    else if (i < 2 * TOTV)   { src = (const float4*)v2; dst = v2b; j = i - TOTV; }
    else                     { src = (const float4*)W;  dst = Wb;  j = i - 2 * TOTV; }
    float4 x = src[j];
    ushort4 o;
    o.x = f2bf(x.x); o.y = f2bf(x.y); o.z = f2bf(x.z); o.w = f2bf(x.w);
    *(ushort4*)&dst[j * 4] = o;
  }
}

// ---------------------------------------------------------------------------
// Kernel 2: projection GEMM  z = elu(v @ W^T + b), bf16 out, + row sum(z^2).
// grid: (512/128, 4096/128, 2)   block: 256   (~2 us; not the bottleneck)
// ---------------------------------------------------------------------------
__global__ __launch_bounds__(256) void proj_kernel(
    const unsigned short* __restrict__ v1b, const unsigned short* __restrict__ v2b,
    const unsigned short* __restrict__ Wb,  const float* __restrict__ bias,
    unsigned short* __restrict__ z1b, unsigned short* __restrict__ z2b,
    float* __restrict__ nsq1, float* __restrict__ nsq2) {
  __shared__ __align__(16) unsigned short As[128 * 32];
  __shared__ __align__(16) unsigned short Bs[128 * 32];
  const int tid = threadIdx.x;
  const int wid = tid >> 6, lane = tid & 63;
  const int wm = wid >> 1, wn = wid & 1;
  const int l15 = lane & 15, l4 = lane >> 4;

  const int zsel = blockIdx.z;
  const unsigned short* Ag = (zsel ? v2b : v1b) + (size_t)blockIdx.y * 128 * DDIM;
  const unsigned short* Bg = Wb + (size_t)blockIdx.x * 128 * DDIM;
  unsigned short* Z = (zsel ? z2b : z1b);
  float* nsq = (zsel ? nsq2 : nsq1);

  f32x4 acc[4][4];
#pragma unroll
  for (int m = 0; m < 4; ++m)
#pragma unroll
    for (int n = 0; n < 4; ++n) acc[m][n] = (f32x4){0.f, 0.f, 0.f, 0.f};

  for (int kt = 0; kt < DDIM; kt += 32) {
#pragma unroll
    for (int i = 0; i < 2; ++i) {
      int off = i * 4096 + tid * 16;
      int row = off >> 6;
      int kb  = off & 63;
      gload_lds16((const char*)(Ag + row * DDIM + kt) + kb,
                  (char*)As + i * 4096 + wid * 1024);
      gload_lds16((const char*)(Bg + row * DDIM + kt) + kb,
                  (char*)Bs + i * 4096 + wid * 1024);
    }
    asm volatile("s_waitcnt vmcnt(0)" ::: "memory");
    __syncthreads();
    short8 av[4], bv[4];
#pragma unroll
    for (int m = 0; m < 4; ++m)
      av[m] = *(const short8*)&As[(wm * 64 + m * 16 + l15) * 32 + l4 * 8];
#pragma unroll
    for (int n = 0; n < 4; ++n)
      bv[n] = *(const short8*)&Bs[(wn * 64 + n * 16 + l15) * 32 + l4 * 8];
#pragma unroll
    for (int m = 0; m < 4; ++m)
#pragma unroll
      for (int n = 0; n < 4; ++n)
        acc[m][n] = __builtin_amdgcn_mfma_f32_16x16x32_bf16(
            av[m], bv[n], acc[m][n], 0, 0, 0);
    __syncthreads();
  }

  const int rowBase = blockIdx.y * 128 + wm * 64;
  const int colBase = blockIdx.x * 128 + wn * 64;
  float bcol[4];
#pragma unroll
  for (int n = 0; n < 4; ++n) bcol[n] = bias[colBase + n * 16 + l15];
#pragma unroll
  for (int m = 0; m < 4; ++m) {
#pragma unroll
    for (int reg = 0; reg < 4; ++reg) {
      int gRow = rowBase + m * 16 + l4 * 4 + reg;
      float rs = 0.f;
#pragma unroll
      for (int n = 0; n < 4; ++n) {
        int gCol = colBase + n * 16 + l15;
        float y = acc[m][n][reg] + bcol[n];
        float zv = (y > 0.f) ? y : expm1f(y);
        unsigned short zb = f2bf(zv);
        Z[(size_t)gRow * DDIM + gCol] = zb;
        float zf = bf2f(zb);
        rs += zf * zf;
      }
      rs += __shfl_xor(rs, 1, 64);
      rs += __shfl_xor(rs, 2, 64);
      rs += __shfl_xor(rs, 4, 64);
      rs += __shfl_xor(rs, 8, 64);
      if (l15 == 0) atomicAdd(&nsq[gRow], rs);
    }
  }
}

// ---------------------------------------------------------------------------
// Kernel 3a: GEMM -> sim = fp8_e4m3(exp(cos/tau)).  R4's proven counted-vmcnt
// 2-buffer pipeline w/ granule swizzle (0 bank conflicts).  Epilogue packs
// fp8 bytes via LDS transpose -> coalesced dwordx4 stores.
// grid: 1024 linear  block: 256.
// ---------------------------------------------------------------------------
__global__ __launch_bounds__(256, 4) void dotsA_kernel(
    const unsigned short* __restrict__ z1b, const unsigned short* __restrict__ z2b,
    const float* __restrict__ nsq1, const float* __restrict__ nsq2,
    unsigned char* __restrict__ sim) {
  __shared__ __align__(16) char smem[2][16384];

  const int tid = threadIdx.x;
  const int wid = tid >> 6, lane = tid & 63;
  const int wm = wid >> 1, wn = wid & 1;
  const int l15 = lane & 15, l4 = lane >> 4;

  const int bid = blockIdx.x;
  const int by = bid >> 5, bx = bid & 31;

  const unsigned short* Ag = z1b + (size_t)by * 128 * DDIM;
  const unsigned short* Bg = z2b + (size_t)bx * 128 * DDIM;

  f32x4 acc[4][4];
#pragma unroll
  for (int m = 0; m < 4; ++m)
#pragma unroll
    for (int n = 0; n < 4; ++n) acc[m][n] = (f32x4){0.f, 0.f, 0.f, 0.f};

#define STAGE(buf, t)                                                          \
  {                                                                            \
    _Pragma("unroll")                                                          \
    for (int i = 0; i < 2; ++i) {                                              \
      int off = i * 4096 + tid * 16;                                           \
      int row = off >> 6;                                                      \
      int gsw = ((off >> 4) & 3) ^ ((row >> 1) & 3);                           \
      gload_lds16((const char*)Ag + row * 1024 + (t) * 64 + gsw * 16,          \
                  smem[buf] + i * 4096 + wid * 1024);                          \
      gload_lds16((const char*)Bg + row * 1024 + (t) * 64 + gsw * 16,          \
                  smem[buf] + 8192 + i * 4096 + wid * 1024);                   \
    }                                                                          \
  }

  STAGE(0, 0);
  STAGE(1, 1);

  const int aswz = (l4 ^ ((l15 >> 1) & 3)) * 8;

#pragma unroll
  for (int t = 0; t < 16; ++t) {
    if (t < 15) asm volatile("s_waitcnt vmcnt(4)" ::: "memory");
    else        asm volatile("s_waitcnt vmcnt(0)" ::: "memory");
    __builtin_amdgcn_s_barrier();
    const unsigned short* As = (const unsigned short*)smem[t & 1];
    const unsigned short* Bs = (const unsigned short*)(smem[t & 1] + 8192);
    short8 av[4], bv[4];
#pragma unroll
    for (int m = 0; m < 4; ++m)
      av[m] = *(const short8*)&As[(wm * 64 + m * 16 + l15) * 32 + aswz];
#pragma unroll
    for (int n = 0; n < 4; ++n)
      bv[n] = *(const short8*)&Bs[(wn * 64 + n * 16 + l15) * 32 + aswz];
#pragma unroll
    for (int m = 0; m < 4; ++m)
#pragma unroll
      for (int n = 0; n < 4; ++n)
        acc[m][n] = __builtin_amdgcn_mfma_f32_16x16x32_bf16(
            av[m], bv[n], acc[m][n], 0, 0, 0);
    __builtin_amdgcn_s_barrier();
    if (t < 14) STAGE(t & 1, t + 2);
  }
#undef STAGE

  const int rowBase = by * 128 + wm * 64;
  const int colBase = bx * 128 + wn * 64;

  float rs2[4], rs1[4][4];
#pragma unroll
  for (int n = 0; n < 4; ++n) rs2[n] = rsqrtf(nsq2[colBase + n * 16 + l15]);
#pragma unroll
  for (int m = 0; m < 4; ++m)
#pragma unroll
    for (int reg = 0; reg < 4; ++reg)
      rs1[m][reg] = rsqrtf(nsq1[rowBase + m * 16 + l4 * 4 + reg]);

  // fp8 bytes -> LDS (smem[0], 128x128 = 16 KB; no overlap with last-read buf 1)
  unsigned char* sB = (unsigned char*)smem;
#pragma unroll
  for (int m = 0; m < 4; ++m)
#pragma unroll
    for (int reg = 0; reg < 4; ++reg) {
      int lrow = wm * 64 + m * 16 + l4 * 4 + reg;
#pragma unroll
      for (int n = 0; n < 4; ++n) {
        float s = __expf(acc[m][n][reg] * (rs1[m][reg] * rs2[n]) * INV_TAU);
        sB[lrow * 128 + wn * 64 + n * 16 + l15] = (unsigned char)f2e4m3(s);
      }
    }
  __syncthreads();
  // coalesced write-out: thread -> row tid>>1, 64B half (tid&1)
  {
    int r = tid >> 1, h = tid & 1;
    const uint4* src = (const uint4*)(sB + r * 128 + h * 64);
    uint4 w0 = src[0], w1 = src[1], w2 = src[2], w3 = src[3];
    uint4* dst = (uint4*)(sim + (size_t)(by * 128 + r) * NROWS + bx * 128 + h * 64);
    dst[0] = w0; dst[1] = w1; dst[2] = w2; dst[3] = w3;
  }
}

// ---------------------------------------------------------------------------
// Kernel 3b: 3-stream reduction, deep-pipelined.  4096 blocks (2x oversub),
// all 12 loads issued up-front, neg stream de-phased by half the sweep
// (block-level channel decorrelation; sim read at both phases).
// ---------------------------------------------------------------------------
__global__ __launch_bounds__(256) void reduce_kernel(
    const unsigned char* __restrict__ sim, const float* __restrict__ pos,
    const float* __restrict__ neg, double* __restrict__ partials) {
  const int tid = threadIdx.x;
  const int gid = blockIdx.x * 256 + tid;
  const int TOT = 4096 * 256;                 // 1,048,576 threads
  const int gidN = (gid + TOT / 2) & (TOT - 1);

  size_t bp0 = (size_t)gid * 8,          bp1 = (size_t)(gid + TOT) * 8;
  size_t bg0 = (size_t)gidN * 8,         bg1 = (size_t)(gidN + TOT) * 8;

  // issue everything (12 loads) before consuming
  float4 p00 = *(const float4*)(pos + bp0);
  float4 p01 = *(const float4*)(pos + bp0 + 4);
  float4 p10 = *(const float4*)(pos + bp1);
  float4 p11 = *(const float4*)(pos + bp1 + 4);
  float4 g00 = *(const float4*)(neg + bg0);
  float4 g01 = *(const float4*)(neg + bg0 + 4);
  float4 g10 = *(const float4*)(neg + bg1);
  float4 g11 = *(const float4*)(neg + bg1 + 4);
  uint2  sp0 = *(const uint2*)(sim + bp0);
  uint2  sp1 = *(const uint2*)(sim + bp1);
  uint2  sg0 = *(const uint2*)(sim + bg0);
  uint2  sg1 = *(const uint2*)(sim + bg1);

  float sumP = 0.f, sumG = 0.f;
#define ACC8(dst, sv, a, b)                                                    \
  {                                                                            \
    unsigned lo = sv.x, hi = sv.y;                                             \
    dst += e4m32f((lo      ) & 0x7Fu) * a.x + e4m32f((lo >>  8) & 0x7Fu) * a.y \
         + e4m32f((lo >> 16) & 0x7Fu) * a.z + e4m32f((lo >> 24) & 0x7Fu) * a.w \
         + e4m32f((hi      ) & 0x7Fu) * b.x + e4m32f((hi >>  8) & 0x7Fu) * b.y \
         + e4m32f((hi >> 16) & 0x7Fu) * b.z + e4m32f((hi >> 24) & 0x7Fu) * b.w;\
  }
  ACC8(sumP, sp0, p00, p01);
  ACC8(sumP, sp1, p10, p11);
  ACC8(sumG, sg0, g00, g01);
  ACC8(sumG, sg1, g10, g11);
#undef ACC8

#pragma unroll
  for (int sft = 1; sft < 64; sft <<= 1) {
    sumP += __shfl_xor(sumP, sft, 64);
    sumG += __shfl_xor(sumG, sft, 64);
  }
  __shared__ float redP[4], redG[4];
  const int wid = tid >> 6;
  if ((tid & 63) == 0) { redP[wid] = sumP; redG[wid] = sumG; }
  __syncthreads();
  if (tid == 0) {
    double tp = (double)redP[0] + redP[1] + redP[2] + redP[3];
    double tg = (double)redG[0] + redG[1] + redG[2] + redG[3];
    partials[2 * blockIdx.x]     = tp;
    partials[2 * blockIdx.x + 1] = tp + tg;   // sumT
  }
}

// ---------------------------------------------------------------------------
// Kernel 4: final reduce of n partial pairs -> -log(sumP / sumT)
// ---------------------------------------------------------------------------
__global__ void finalize_kernel(const double* __restrict__ partials, int n,
                                float* __restrict__ out) {
  __shared__ double sp[256], st[256];
  int t = threadIdx.x;
  double a = 0.0, b = 0.0;
  for (int i = t; i < n; i += 256) {
    a += partials[2 * i];
    b += partials[2 * i + 1];
  }
  sp[t] = a; st[t] = b;
  __syncthreads();
  for (int s = 128; s > 0; s >>= 1) {
    if (t < s) { sp[t] += sp[t + s]; st[t] += st[t + s]; }
    __syncthreads();
  }
  if (t == 0) out[0] = (float)(log(st[0]) - log(sp[0]));
}

// ---------------------------------------------------------------------------
extern "C" void kernel_launch(void* const* d_in, const int* in_sizes, int n_in,
                              void* d_out, int out_size, void* d_ws, size_t ws_size,
                              hipStream_t stream) {
  (void)in_sizes; (void)n_in; (void)out_size; (void)ws_size;
  const float* v1   = (const float*)d_in[0];
  const float* v2   = (const float*)d_in[1];
  const float* pos  = (const float*)d_in[2];
  const float* neg  = (const float*)d_in[3];
  const float* W    = (const float*)d_in[4];
  const float* bias = (const float*)d_in[5];

  char* ws = (char*)d_ws;
  unsigned short* z1b = (unsigned short*)(ws + 0);         // 4 MiB
  unsigned short* z2b = (unsigned short*)(ws + 4194304);   // 4 MiB
  float* nsq1         = (float*)(ws + 8388608);            // 16 KiB
  float* nsq2         = (float*)(ws + 8404992);            // 16 KiB
  double* partials    = (double*)(ws + 8421376);           // 64 KiB (4096 pairs)
  unsigned short* v1b = (unsigned short*)(ws + 8486912);   // 4 MiB
  unsigned short* v2b = (unsigned short*)(ws + 12681216);  // 4 MiB
  unsigned short* Wb  = (unsigned short*)(ws + 16875520);  // 512 KiB
  unsigned char*  sim = (unsigned char*)(ws + 17399808);   // 16 MiB fp8
  float* out = (float*)d_out;

  hipLaunchKernelGGL(convert_kernel, dim3(1024), dim3(256), 0, stream,
                     v1, v2, W, v1b, v2b, Wb, nsq1, nsq2);
  hipLaunchKernelGGL(proj_kernel, dim3(DDIM / 128, NROWS / 128, 2), dim3(256), 0, stream,
                     v1b, v2b, Wb, bias, z1b, z2b, nsq1, nsq2);
  hipLaunchKernelGGL(dotsA_kernel, dim3(1024), dim3(256), 0, stream,
                     z1b, z2b, nsq1, nsq2, sim);
  hipLaunchKernelGGL(reduce_kernel, dim3(4096), dim3(256), 0, stream,
                     sim, pos, neg, partials);
  hipLaunchKernelGGL(finalize_kernel, dim3(1), dim3(256), 0, stream,
                     partials, 4096, out);
}

// Round 10
// 86.480 us; speedup vs baseline: 1.0176x; 1.0176x over previous
//
#include <hip/hip_runtime.h>
#include <hip/hip_bf16.h>
#include <math.h>

#define NROWS 4096
#define DDIM  512
#define INV_TAU 1.25f

typedef __attribute__((ext_vector_type(8))) short short8;
typedef __attribute__((ext_vector_type(4))) float f32x4;

__device__ inline void gload_lds16(const void* g, void* l) {
  __builtin_amdgcn_global_load_lds(
      (const __attribute__((address_space(1))) void*)g,
      (__attribute__((address_space(3))) void*)l, 16, 0, 0);
}

__device__ inline unsigned short f2bf(float f) {
  __hip_bfloat16 h = __float2bfloat16(f);
  return __builtin_bit_cast(unsigned short, h);
}
__device__ inline float bf2f(unsigned short u) {
  return __bfloat162float(__builtin_bit_cast(__hip_bfloat16, u));
}

// fp8 e4m3 (positive-only range used: s in [0.28, 3.6], all normal)
__device__ inline unsigned f2e4m3(float s) {
  unsigned b = __builtin_bit_cast(unsigned, s);
  return (b + 0x80000u - 0x3C000000u) >> 20;   // round-nearest, exp bias 7
}
__device__ inline float e4m32f(unsigned u8) {
  return __builtin_bit_cast(float, (u8 << 20) + 0x3C000000u);
}

// ---------------------------------------------------------------------------
// Kernel 1: f32 -> bf16 conversion for v1, v2, W ; zero the nsq accumulators.
// ---------------------------------------------------------------------------
__global__ void convert_kernel(const float* __restrict__ v1,
                               const float* __restrict__ v2,
                               const float* __restrict__ W,
                               unsigned short* __restrict__ v1b,
                               unsigned short* __restrict__ v2b,
                               unsigned short* __restrict__ Wb,
                               float* __restrict__ nsq1,
                               float* __restrict__ nsq2) {
  int idx = blockIdx.x * blockDim.x + threadIdx.x;
  if (idx < NROWS) { nsq1[idx] = 0.f; nsq2[idx] = 0.f; }
  const int TOTV = (NROWS * DDIM) / 4;
  const int TOTW = (DDIM * DDIM) / 4;
  const int total = 2 * TOTV + TOTW;
  const int stride = gridDim.x * blockDim.x;
  for (int i = idx; i < total; i += stride) {
    const float4* src; unsigned short* dst; int j;
    if (i < TOTV)            { src = (const float4*)v1; dst = v1b; j = i; }
    else if (i < 2 * TOTV)   { src = (const float4*)v2; dst = v2b; j = i - TOTV; }
    else                     { src = (const float4*)W;  dst = Wb;  j = i - 2 * TOTV; }
    float4 x = src[j];
    ushort4 o;
    o.x = f2bf(x.x); o.y = f2bf(x.y); o.z = f2bf(x.z); o.w = f2bf(x.w);
    *(ushort4*)&dst[j * 4] = o;
  }
}

// ---------------------------------------------------------------------------
// Kernel 2: projection GEMM  z = elu(v @ W^T + b), bf16 out, + row sum(z^2).
// grid: (512/128, 4096/128, 2)   block: 256   (~2 us; not the bottleneck)
// ---------------------------------------------------------------------------
__global__ __launch_bounds__(256) void proj_kernel(
    const unsigned short* __restrict__ v1b, const unsigned short* __restrict__ v2b,
    const unsigned short* __restrict__ Wb,  const float* __restrict__ bias,
    unsigned short* __restrict__ z1b, unsigned short* __restrict__ z2b,
    float* __restrict__ nsq1, float* __restrict__ nsq2) {
  __shared__ __align__(16) unsigned short As[128 * 32];
  __shared__ __align__(16) unsigned short Bs[128 * 32];
  const int tid = threadIdx.x;
  const int wid = tid >> 6, lane = tid & 63;
  const int wm = wid >> 1, wn = wid & 1;
  const int l15 = lane & 15, l4 = lane >> 4;

  const int zsel = blockIdx.z;
  const unsigned short* Ag = (zsel ? v2b : v1b) + (size_t)blockIdx.y * 128 * DDIM;
  const unsigned short* Bg = Wb + (size_t)blockIdx.x * 128 * DDIM;
  unsigned short* Z = (zsel ? z2b : z1b);
  float* nsq = (zsel ? nsq2 : nsq1);

  f32x4 acc[4][4];
#pragma unroll
  for (int m = 0; m < 4; ++m)
#pragma unroll
    for (int n = 0; n < 4; ++n) acc[m][n] = (f32x4){0.f, 0.f, 0.f, 0.f};

  for (int kt = 0; kt < DDIM; kt += 32) {
#pragma unroll
    for (int i = 0; i < 2; ++i) {
      int off = i * 4096 + tid * 16;
      int row = off >> 6;
      int kb  = off & 63;
      gload_lds16((const char*)(Ag + row * DDIM + kt) + kb,
                  (char*)As + i * 4096 + wid * 1024);
      gload_lds16((const char*)(Bg + row * DDIM + kt) + kb,
                  (char*)Bs + i * 4096 + wid * 1024);
    }
    asm volatile("s_waitcnt vmcnt(0)" ::: "memory");
    __syncthreads();
    short8 av[4], bv[4];
#pragma unroll
    for (int m = 0; m < 4; ++m)
      av[m] = *(const short8*)&As[(wm * 64 + m * 16 + l15) * 32 + l4 * 8];
#pragma unroll
    for (int n = 0; n < 4; ++n)
      bv[n] = *(const short8*)&Bs[(wn * 64 + n * 16 + l15) * 32 + l4 * 8];
#pragma unroll
    for (int m = 0; m < 4; ++m)
#pragma unroll
      for (int n = 0; n < 4; ++n)
        acc[m][n] = __builtin_amdgcn_mfma_f32_16x16x32_bf16(
            av[m], bv[n], acc[m][n], 0, 0, 0);
    __syncthreads();
  }

  const int rowBase = blockIdx.y * 128 + wm * 64;
  const int colBase = blockIdx.x * 128 + wn * 64;
  float bcol[4];
#pragma unroll
  for (int n = 0; n < 4; ++n) bcol[n] = bias[colBase + n * 16 + l15];
#pragma unroll
  for (int m = 0; m < 4; ++m) {
#pragma unroll
    for (int reg = 0; reg < 4; ++reg) {
      int gRow = rowBase + m * 16 + l4 * 4 + reg;
      float rs = 0.f;
#pragma unroll
      for (int n = 0; n < 4; ++n) {
        int gCol = colBase + n * 16 + l15;
        float y = acc[m][n][reg] + bcol[n];
        float zv = (y > 0.f) ? y : expm1f(y);
        unsigned short zb = f2bf(zv);
        Z[(size_t)gRow * DDIM + gCol] = zb;
        float zf = bf2f(zb);
        rs += zf * zf;
      }
      rs += __shfl_xor(rs, 1, 64);
      rs += __shfl_xor(rs, 2, 64);
      rs += __shfl_xor(rs, 4, 64);
      rs += __shfl_xor(rs, 8, 64);
      if (l15 == 0) atomicAdd(&nsq[gRow], rs);
    }
  }
}

// ---------------------------------------------------------------------------
// Kernel 3a: GEMM -> sim = fp8_e4m3(exp(cos/tau)).  R4's proven counted-vmcnt
// 2-buffer pipeline w/ granule swizzle (0 bank conflicts).  Epilogue packs
// fp8 bytes via LDS transpose -> coalesced dwordx4 stores.
// grid: 1024 linear  block: 256.
// ---------------------------------------------------------------------------
__global__ __launch_bounds__(256, 4) void dotsA_kernel(
    const unsigned short* __restrict__ z1b, const unsigned short* __restrict__ z2b,
    const float* __restrict__ nsq1, const float* __restrict__ nsq2,
    unsigned char* __restrict__ sim) {
  __shared__ __align__(16) char smem[2][16384];

  const int tid = threadIdx.x;
  const int wid = tid >> 6, lane = tid & 63;
  const int wm = wid >> 1, wn = wid & 1;
  const int l15 = lane & 15, l4 = lane >> 4;

  const int bid = blockIdx.x;
  const int by = bid >> 5, bx = bid & 31;

  const unsigned short* Ag = z1b + (size_t)by * 128 * DDIM;
  const unsigned short* Bg = z2b + (size_t)bx * 128 * DDIM;

  f32x4 acc[4][4];
#pragma unroll
  for (int m = 0; m < 4; ++m)
#pragma unroll
    for (int n = 0; n < 4; ++n) acc[m][n] = (f32x4){0.f, 0.f, 0.f, 0.f};

#define STAGE(buf, t)                                                          \
  {                                                                            \
    _Pragma("unroll")                                                          \
    for (int i = 0; i < 2; ++i) {                                              \
      int off = i * 4096 + tid * 16;                                           \
      int row = off >> 6;                                                      \
      int gsw = ((off >> 4) & 3) ^ ((row >> 1) & 3);                           \
      gload_lds16((const char*)Ag + row * 1024 + (t) * 64 + gsw * 16,          \
                  smem[buf] + i * 4096 + wid * 1024);                          \
      gload_lds16((const char*)Bg + row * 1024 + (t) * 64 + gsw * 16,          \
                  smem[buf] + 8192 + i * 4096 + wid * 1024);                   \
    }                                                                          \
  }

  STAGE(0, 0);
  STAGE(1, 1);

  const int aswz = (l4 ^ ((l15 >> 1) & 3)) * 8;

#pragma unroll
  for (int t = 0; t < 16; ++t) {
    if (t < 15) asm volatile("s_waitcnt vmcnt(4)" ::: "memory");
    else        asm volatile("s_waitcnt vmcnt(0)" ::: "memory");
    __builtin_amdgcn_s_barrier();
    const unsigned short* As = (const unsigned short*)smem[t & 1];
    const unsigned short* Bs = (const unsigned short*)(smem[t & 1] + 8192);
    short8 av[4], bv[4];
#pragma unroll
    for (int m = 0; m < 4; ++m)
      av[m] = *(const short8*)&As[(wm * 64 + m * 16 + l15) * 32 + aswz];
#pragma unroll
    for (int n = 0; n < 4; ++n)
      bv[n] = *(const short8*)&Bs[(wn * 64 + n * 16 + l15) * 32 + aswz];
#pragma unroll
    for (int m = 0; m < 4; ++m)
#pragma unroll
      for (int n = 0; n < 4; ++n)
        acc[m][n] = __builtin_amdgcn_mfma_f32_16x16x32_bf16(
            av[m], bv[n], acc[m][n], 0, 0, 0);
    __builtin_amdgcn_s_barrier();
    if (t < 14) STAGE(t & 1, t + 2);
  }
#undef STAGE

  const int rowBase = by * 128 + wm * 64;
  const int colBase = bx * 128 + wn * 64;

  float rs2[4], rs1[4][4];
#pragma unroll
  for (int n = 0; n < 4; ++n) rs2[n] = rsqrtf(nsq2[colBase + n * 16 + l15]);
#pragma unroll
  for (int m = 0; m < 4; ++m)
#pragma unroll
    for (int reg = 0; reg < 4; ++reg)
      rs1[m][reg] = rsqrtf(nsq1[rowBase + m * 16 + l4 * 4 + reg]);

  // fp8 bytes -> LDS (smem[0], 128x128 = 16 KB; no overlap with last-read buf 1)
  unsigned char* sB = (unsigned char*)smem;
#pragma unroll
  for (int m = 0; m < 4; ++m)
#pragma unroll
    for (int reg = 0; reg < 4; ++reg) {
      int lrow = wm * 64 + m * 16 + l4 * 4 + reg;
#pragma unroll
      for (int n = 0; n < 4; ++n) {
        float s = __expf(acc[m][n][reg] * (rs1[m][reg] * rs2[n]) * INV_TAU);
        sB[lrow * 128 + wn * 64 + n * 16 + l15] = (unsigned char)f2e4m3(s);
      }
    }
  __syncthreads();
  // coalesced write-out: thread -> row tid>>1, 64B half (tid&1)
  {
    int r = tid >> 1, h = tid & 1;
    const uint4* src = (const uint4*)(sB + r * 128 + h * 64);
    uint4 w0 = src[0], w1 = src[1], w2 = src[2], w3 = src[3];
    uint4* dst = (uint4*)(sim + (size_t)(by * 128 + r) * NROWS + bx * 128 + h * 64);
    dst[0] = w0; dst[1] = w1; dst[2] = w2; dst[3] = w3;
  }
}

// ---------------------------------------------------------------------------
// Kernel 3b: 3-stream reduction, WAVE-COHERENT addressing: each instruction's
// 64 lanes read lane-consecutive float4 (1 KB contiguous, 16 cache lines —
// same as m13's 6.3 TB/s probe).  Wave w owns elements [w*1024, w*1024+1024).
// pos/neg via nontemporal loads (read-once).  grid: 4096  block: 256.
// ---------------------------------------------------------------------------
__global__ __launch_bounds__(256) void reduce_kernel(
    const unsigned char* __restrict__ sim, const float* __restrict__ pos,
    const float* __restrict__ neg, double* __restrict__ partials) {
  const int tid = threadIdx.x;
  const int lane = tid & 63;
  const int wave = (blockIdx.x * 256 + tid) >> 6;       // 0..16383
  const size_t base = (size_t)wave * 1024 + (size_t)lane * 4;  // element idx

  // issue all 12 loads before consuming; every instruction lane-consecutive
  f32x4 p[4], g[4]; unsigned s[4];
#pragma unroll
  for (int it = 0; it < 4; ++it) {
    size_t off = base + (size_t)it * 256;
    p[it] = __builtin_nontemporal_load((const f32x4*)(pos + off));
    g[it] = __builtin_nontemporal_load((const f32x4*)(neg + off));
    s[it] = *(const unsigned*)(sim + off);
  }

  float sumP = 0.f, sumG = 0.f;
#pragma unroll
  for (int it = 0; it < 4; ++it) {
    float s0 = e4m32f((s[it]      ) & 0x7Fu);
    float s1 = e4m32f((s[it] >>  8) & 0x7Fu);
    float s2 = e4m32f((s[it] >> 16) & 0x7Fu);
    float s3 = e4m32f((s[it] >> 24) & 0x7Fu);
    sumP += s0 * p[it][0] + s1 * p[it][1] + s2 * p[it][2] + s3 * p[it][3];
    sumG += s0 * g[it][0] + s1 * g[it][1] + s2 * g[it][2] + s3 * g[it][3];
  }

#pragma unroll
  for (int sft = 1; sft < 64; sft <<= 1) {
    sumP += __shfl_xor(sumP, sft, 64);
    sumG += __shfl_xor(sumG, sft, 64);
  }
  __shared__ float redP[4], redG[4];
  const int wid = tid >> 6;
  if (lane == 0) { redP[wid] = sumP; redG[wid] = sumG; }
  __syncthreads();
  if (tid == 0) {
    double tp = (double)redP[0] + redP[1] + redP[2] + redP[3];
    double tg = (double)redG[0] + redG[1] + redG[2] + redG[3];
    partials[2 * blockIdx.x]     = tp;
    partials[2 * blockIdx.x + 1] = tp + tg;   // sumT
  }
}

// ---------------------------------------------------------------------------
// Kernel 4: final reduce of n partial pairs -> -log(sumP / sumT)
// ---------------------------------------------------------------------------
__global__ void finalize_kernel(const double* __restrict__ partials, int n,
                                float* __restrict__ out) {
  __shared__ double sp[256], st[256];
  int t = threadIdx.x;
  double a = 0.0, b = 0.0;
  for (int i = t; i < n; i += 256) {
    a += partials[2 * i];
    b += partials[2 * i + 1];
  }
  sp[t] = a; st[t] = b;
  __syncthreads();
  for (int s = 128; s > 0; s >>= 1) {
    if (t < s) { sp[t] += sp[t + s]; st[t] += st[t + s]; }
    __syncthreads();
  }
  if (t == 0) out[0] = (float)(log(st[0]) - log(sp[0]));
}

// ---------------------------------------------------------------------------
extern "C" void kernel_launch(void* const* d_in, const int* in_sizes, int n_in,
                              void* d_out, int out_size, void* d_ws, size_t ws_size,
                              hipStream_t stream) {
  (void)in_sizes; (void)n_in; (void)out_size; (void)ws_size;
  const float* v1   = (const float*)d_in[0];
  const float* v2   = (const float*)d_in[1];
  const float* pos  = (const float*)d_in[2];
  const float* neg  = (const float*)d_in[3];
  const float* W    = (const float*)d_in[4];
  const float* bias = (const float*)d_in[5];

  char* ws = (char*)d_ws;
  unsigned short* z1b = (unsigned short*)(ws + 0);         // 4 MiB
  unsigned short* z2b = (unsigned short*)(ws + 4194304);   // 4 MiB
  float* nsq1         = (float*)(ws + 8388608);            // 16 KiB
  float* nsq2         = (float*)(ws + 8404992);            // 16 KiB
  double* partials    = (double*)(ws + 8421376);           // 64 KiB (4096 pairs)
  unsigned short* v1b = (unsigned short*)(ws + 8486912);   // 4 MiB
  unsigned short* v2b = (unsigned short*)(ws + 12681216);  // 4 MiB
  unsigned short* Wb  = (unsigned short*)(ws + 16875520);  // 512 KiB
  unsigned char*  sim = (unsigned char*)(ws + 17399808);   // 16 MiB fp8
  float* out = (float*)d_out;

  hipLaunchKernelGGL(convert_kernel, dim3(1024), dim3(256), 0, stream,
                     v1, v2, W, v1b, v2b, Wb, nsq1, nsq2);
  hipLaunchKernelGGL(proj_kernel, dim3(DDIM / 128, NROWS / 128, 2), dim3(256), 0, stream,
                     v1b, v2b, Wb, bias, z1b, z2b, nsq1, nsq2);
  hipLaunchKernelGGL(dotsA_kernel, dim3(1024), dim3(256), 0, stream,
                     z1b, z2b, nsq1, nsq2, sim);
  hipLaunchKernelGGL(reduce_kernel, dim3(4096), dim3(256), 0, stream,
                     sim, pos, neg, partials);
  hipLaunchKernelGGL(finalize_kernel, dim3(1), dim3(256), 0, stream,
                     partials, 4096, out);
}